// Round 1
// baseline (476.322 us; speedup 1.0000x reference)
//
#include <hip/hip_runtime.h>

// SWT inverse, dilation=1, circular padding, Haar-like 2-tap kernels.
// out[h,w] = 0.125 * ( A[h,w-1] + B[h,w] )   (indices mod 256), where
//   A(h,c) = P(h-1,c) + Q(h,c),  B(h,c) = R(h-1,c) + T(h,c)
//   P = LL+LH+HL+HH, Q = LL+LH-HL-HH, R = LL-LH+HL-HH, T = LL-LH-HL+HH
// Coefficient magnitude 0.25*(1/sqrt(2))^2 == 0.125 (exact to ~1e-8 rel).
//
// v2 vs v1 (492 us):
//  - A[w-1] via wave rotate (__shfl, lane-1 mod 64) instead of 8 scalar
//    edge loads per row-iter: VMEM instrs/iter 17 -> 5. W=256 spans the
//    64-lane wave exactly (4 cols/lane), so the wrap is the wave wrap.
//  - 2-level butterfly for P/Q/R/T; P,R carried across rows in registers.
//  - nontemporal store for the write-once output.

static constexpr int HH_ = 256;   // H
static constexpr int WW_ = 256;   // W
static constexpr int RPT = 16;    // rows per thread

typedef float f4 __attribute__((ext_vector_type(4)));

__global__ __launch_bounds__(256) void swt_inv_kernel(
    const float* __restrict__ LL, const float* __restrict__ LH,
    const float* __restrict__ HL, const float* __restrict__ HH,
    float* __restrict__ out)
{
    // blockIdx.x = plane*4 + slab ; slab = 64 rows of one (b,c) plane
    const int slab  = blockIdx.x & 3;
    const int plane = blockIdx.x >> 2;
    const size_t poff = (size_t)plane * (HH_ * WW_);

    const int tx = threadIdx.x & 63;   // column group: 4 pixels
    const int ty = threadIdx.x >> 6;   // row strip within slab
    const int w  = tx << 2;
    const int h0 = slab * 64 + ty * RPT;
    const int srcLane = (tx + 63) & 63;  // lane holding column w-1 (its A.w)

    const float* ll = LL + poff + w;
    const float* lh = LH + poff + w;
    const float* hl = HL + poff + w;
    const float* hh = HH + poff + w;
    float* op = out + poff + w;

    // preload previous row (h0-1, wrapped); only P,R of it are needed
    const int hp = (h0 == 0) ? (HH_ - 1) : (h0 - 1);
    f4 Pp, Rp;
    {
        const int r = hp * WW_;
        f4 a = *(const f4*)(ll + r);
        f4 b = *(const f4*)(lh + r);
        f4 c = *(const f4*)(hl + r);
        f4 d = *(const f4*)(hh + r);
        f4 u0 = a + b, u1 = a - b, v0 = c + d, v1 = c - d;
        Pp = u0 + v0;
        Rp = u1 + v1;
    }

    #pragma unroll 4
    for (int i = 0; i < RPT; ++i) {
        const int r = (h0 + i) * WW_;
        f4 a = *(const f4*)(ll + r);
        f4 b = *(const f4*)(lh + r);
        f4 c = *(const f4*)(hl + r);
        f4 d = *(const f4*)(hh + r);

        // butterfly: P,Q,R,T in 8 ops/component
        f4 u0 = a + b, u1 = a - b, v0 = c + d, v1 = c - d;
        f4 Aq = Pp + (u0 - v0);   // A at columns w..w+3
        f4 Bq = Rp + (u1 - v1);   // B at columns w..w+3
        Pp = u0 + v0;             // becomes P(prev) for next row
        Rp = u1 + v1;             // becomes R(prev) for next row

        // A at column w-1 = left lane's Aq.w (wave-wrap handles w==0)
        const float Am = __shfl(Aq.w, srcLane, 64);

        f4 o;
        o.x = 0.125f * (Am   + Bq.x);
        o.y = 0.125f * (Aq.x + Bq.y);
        o.z = 0.125f * (Aq.y + Bq.z);
        o.w = 0.125f * (Aq.z + Bq.w);
        __builtin_nontemporal_store(o, (f4*)(op + r));
    }
}

extern "C" void kernel_launch(void* const* d_in, const int* in_sizes, int n_in,
                              void* d_out, int out_size, void* d_ws, size_t ws_size,
                              hipStream_t stream) {
    const float* LL = (const float*)d_in[0];
    const float* LH = (const float*)d_in[1];
    const float* HL = (const float*)d_in[2];
    const float* HH = (const float*)d_in[3];
    float* out = (float*)d_out;

    const int planes = out_size / (HH_ * WW_);   // B*C = 512
    dim3 grid(planes * 4);                        // 4 slabs of 64 rows each
    dim3 block(256);
    swt_inv_kernel<<<grid, block, 0, stream>>>(LL, LH, HL, HH, out);
}

// Round 2
// 474.058 us; speedup vs baseline: 1.0048x; 1.0048x over previous
//
#include <hip/hip_runtime.h>

// SWT inverse, dilation=1, circular padding, Haar-like 2-tap kernels.
// out[h,w] = 0.125 * ( A[h,w-1] + B[h,w] )   (indices mod 256), where
//   A(h,c) = P(h-1,c) + Q(h,c),  B(h,c) = R(h-1,c) + T(h,c)
//   P = LL+LH+HL+HH, Q = LL+LH-HL-HH, R = LL-LH+HL-HH, T = LL-LH-HL+HH
// Coefficient magnitude 0.25*(1/sqrt(2))^2 == 0.125 (exact to ~1e-8 rel).
//
// v3 vs v2 (rocprof 185 us, 2.26 TB/s, VALUBusy 4%, VGPR 32):
//  - explicit 1-row software pipeline: next row's 4 loads issued BEFORE
//    current row's butterfly -> 8 loads in flight/wave (vmcnt(4), not
//    vmcnt(0)); VGPR ~32 -> ~60 (still 8 waves/SIMD).
//  - 128-thread blocks (2 waves x 16-row strips), grid 4096 = 2x
//    oversubscription (16 blocks/CU resident) to smooth ramp/tail that
//    showed as OccupancyPercent 67.
//  - keeps v2's shfl left-tap (W=256 spans the 64-lane wave exactly),
//    butterfly P/R row-carry, nontemporal store.

static constexpr int HH_ = 256;   // H
static constexpr int WW_ = 256;   // W
static constexpr int RPT = 16;    // rows per wave-strip
static constexpr int SLABS = HH_ / (2 * RPT);   // 8 slabs of 32 rows

typedef float f4 __attribute__((ext_vector_type(4)));

__global__ __launch_bounds__(128) void swt_inv_kernel(
    const float* __restrict__ LL, const float* __restrict__ LH,
    const float* __restrict__ HL, const float* __restrict__ HH,
    float* __restrict__ out)
{
    // blockIdx.x = plane*8 + slab ; slab = 32 rows of one (b,c) plane
    const int slab  = blockIdx.x & (SLABS - 1);
    const int plane = blockIdx.x >> 3;
    const size_t poff = (size_t)plane * (HH_ * WW_);

    const int tx = threadIdx.x & 63;   // column group: 4 pixels
    const int ty = threadIdx.x >> 6;   // 0 or 1: strip within slab
    const int w  = tx << 2;
    const int h0 = slab * (2 * RPT) + ty * RPT;
    const int srcLane = (tx + 63) & 63;  // lane holding column w-1 (its A.w)

    const float* ll = LL + poff + w;
    const float* lh = LH + poff + w;
    const float* hl = HL + poff + w;
    const float* hh = HH + poff + w;
    float* op = out + poff + w;

    // previous row (h0-1, wrapped); only P,R of it are needed
    const int hp = (h0 == 0) ? (HH_ - 1) : (h0 - 1);
    f4 Pp, Rp;
    {
        const int r = hp * WW_;
        f4 a = *(const f4*)(ll + r);
        f4 b = *(const f4*)(lh + r);
        f4 c = *(const f4*)(hl + r);
        f4 d = *(const f4*)(hh + r);
        f4 u0 = a + b, u1 = a - b, v0 = c + d, v1 = c - d;
        Pp = u0 + v0;
        Rp = u1 + v1;
    }

    // preload row h0 (pipeline prologue)
    f4 a0 = *(const f4*)(ll + h0 * WW_);
    f4 b0 = *(const f4*)(lh + h0 * WW_);
    f4 c0 = *(const f4*)(hl + h0 * WW_);
    f4 d0 = *(const f4*)(hh + h0 * WW_);

    #pragma unroll
    for (int i = 0; i < RPT; ++i) {
        const int rc = (h0 + i) * WW_;

        // issue next row's loads before touching this row's data
        f4 a1, b1, c1, d1;
        if (i + 1 < RPT) {
            const int rn = rc + WW_;
            a1 = *(const f4*)(ll + rn);
            b1 = *(const f4*)(lh + rn);
            c1 = *(const f4*)(hl + rn);
            d1 = *(const f4*)(hh + rn);
        }

        // butterfly: P,Q,R,T in 8 ops/component
        f4 u0 = a0 + b0, u1 = a0 - b0, v0 = c0 + d0, v1 = c0 - d0;
        f4 Aq = Pp + (u0 - v0);   // A at columns w..w+3
        f4 Bq = Rp + (u1 - v1);   // B at columns w..w+3
        Pp = u0 + v0;             // becomes P(prev) for next row
        Rp = u1 + v1;             // becomes R(prev) for next row

        // A at column w-1 = left lane's Aq.w (wave-wrap handles w==0)
        const float Am = __shfl(Aq.w, srcLane, 64);

        f4 o;
        o.x = 0.125f * (Am   + Bq.x);
        o.y = 0.125f * (Aq.x + Bq.y);
        o.z = 0.125f * (Aq.y + Bq.z);
        o.w = 0.125f * (Aq.z + Bq.w);
        __builtin_nontemporal_store(o, (f4*)(op + rc));

        a0 = a1; b0 = b1; c0 = c1; d0 = d1;
    }
}

extern "C" void kernel_launch(void* const* d_in, const int* in_sizes, int n_in,
                              void* d_out, int out_size, void* d_ws, size_t ws_size,
                              hipStream_t stream) {
    const float* LL = (const float*)d_in[0];
    const float* LH = (const float*)d_in[1];
    const float* HL = (const float*)d_in[2];
    const float* HH = (const float*)d_in[3];
    float* out = (float*)d_out;

    const int planes = out_size / (HH_ * WW_);   // B*C = 512
    dim3 grid(planes * SLABS);                    // 4096 blocks of 32 rows
    dim3 block(128);
    swt_inv_kernel<<<grid, block, 0, stream>>>(LL, LH, HL, HH, out);
}

// Round 3
// 455.274 us; speedup vs baseline: 1.0462x; 1.0413x over previous
//
#include <hip/hip_runtime.h>

// SWT inverse, dilation=1, circular padding, Haar-like 2-tap kernels.
// out[h,w] = 0.125 * ( A[h,w-1] + B[h,w] )   (indices mod 256), where
//   A(h,c) = P(h-1,c) + Q(h,c),  B(h,c) = R(h-1,c) + T(h,c)
//   P = LL+LH+HL+HH, Q = LL+LH-HL-HH, R = LL-LH+HL-HH, T = LL-LH-HL+HH
// Coefficient magnitude 0.25*(1/sqrt(2))^2 == 0.125 (exact to ~1e-8 rel).
//
// v4 = v3 with NONTEMPORAL input loads (L3 no-allocate probe).
// v2/v3 rocprof: 183-186 us, HBM 2.27 TB/s, VALU 4.7%, FETCH 285 MB of a
// 537 MB input set (47% L3 carryover). Three structural variants tied ->
// service-rate-bound, not latency-bound. This version discriminates
// L3-churn vs TLB vs DRAM-pattern limits by bypassing L3 allocation on
// the 4 streaming input reads.

static constexpr int HH_ = 256;   // H
static constexpr int WW_ = 256;   // W
static constexpr int RPT = 16;    // rows per wave-strip
static constexpr int SLABS = HH_ / (2 * RPT);   // 8 slabs of 32 rows

typedef float f4 __attribute__((ext_vector_type(4)));

__global__ __launch_bounds__(128) void swt_inv_kernel(
    const float* __restrict__ LL, const float* __restrict__ LH,
    const float* __restrict__ HL, const float* __restrict__ HH,
    float* __restrict__ out)
{
    // blockIdx.x = plane*8 + slab ; slab = 32 rows of one (b,c) plane
    const int slab  = blockIdx.x & (SLABS - 1);
    const int plane = blockIdx.x >> 3;
    const size_t poff = (size_t)plane * (HH_ * WW_);

    const int tx = threadIdx.x & 63;   // column group: 4 pixels
    const int ty = threadIdx.x >> 6;   // 0 or 1: strip within slab
    const int w  = tx << 2;
    const int h0 = slab * (2 * RPT) + ty * RPT;
    const int srcLane = (tx + 63) & 63;  // lane holding column w-1 (its A.w)

    const float* ll = LL + poff + w;
    const float* lh = LH + poff + w;
    const float* hl = HL + poff + w;
    const float* hh = HH + poff + w;
    float* op = out + poff + w;

    // previous row (h0-1, wrapped); only P,R of it are needed
    const int hp = (h0 == 0) ? (HH_ - 1) : (h0 - 1);
    f4 Pp, Rp;
    {
        const int r = hp * WW_;
        f4 a = __builtin_nontemporal_load((const f4*)(ll + r));
        f4 b = __builtin_nontemporal_load((const f4*)(lh + r));
        f4 c = __builtin_nontemporal_load((const f4*)(hl + r));
        f4 d = __builtin_nontemporal_load((const f4*)(hh + r));
        f4 u0 = a + b, u1 = a - b, v0 = c + d, v1 = c - d;
        Pp = u0 + v0;
        Rp = u1 + v1;
    }

    // preload row h0 (pipeline prologue)
    f4 a0 = __builtin_nontemporal_load((const f4*)(ll + h0 * WW_));
    f4 b0 = __builtin_nontemporal_load((const f4*)(lh + h0 * WW_));
    f4 c0 = __builtin_nontemporal_load((const f4*)(hl + h0 * WW_));
    f4 d0 = __builtin_nontemporal_load((const f4*)(hh + h0 * WW_));

    #pragma unroll
    for (int i = 0; i < RPT; ++i) {
        const int rc = (h0 + i) * WW_;

        // issue next row's loads before touching this row's data
        f4 a1, b1, c1, d1;
        if (i + 1 < RPT) {
            const int rn = rc + WW_;
            a1 = __builtin_nontemporal_load((const f4*)(ll + rn));
            b1 = __builtin_nontemporal_load((const f4*)(lh + rn));
            c1 = __builtin_nontemporal_load((const f4*)(hl + rn));
            d1 = __builtin_nontemporal_load((const f4*)(hh + rn));
        }

        // butterfly: P,Q,R,T in 8 ops/component
        f4 u0 = a0 + b0, u1 = a0 - b0, v0 = c0 + d0, v1 = c0 - d0;
        f4 Aq = Pp + (u0 - v0);   // A at columns w..w+3
        f4 Bq = Rp + (u1 - v1);   // B at columns w..w+3
        Pp = u0 + v0;             // becomes P(prev) for next row
        Rp = u1 + v1;             // becomes R(prev) for next row

        // A at column w-1 = left lane's Aq.w (wave-wrap handles w==0)
        const float Am = __shfl(Aq.w, srcLane, 64);

        f4 o;
        o.x = 0.125f * (Am   + Bq.x);
        o.y = 0.125f * (Aq.x + Bq.y);
        o.z = 0.125f * (Aq.y + Bq.z);
        o.w = 0.125f * (Aq.z + Bq.w);
        __builtin_nontemporal_store(o, (f4*)(op + rc));

        a0 = a1; b0 = b1; c0 = c1; d0 = d1;
    }
}

extern "C" void kernel_launch(void* const* d_in, const int* in_sizes, int n_in,
                              void* d_out, int out_size, void* d_ws, size_t ws_size,
                              hipStream_t stream) {
    const float* LL = (const float*)d_in[0];
    const float* LH = (const float*)d_in[1];
    const float* HL = (const float*)d_in[2];
    const float* HH = (const float*)d_in[3];
    float* out = (float*)d_out;

    const int planes = out_size / (HH_ * WW_);   // B*C = 512
    dim3 grid(planes * SLABS);                    // 4096 blocks of 32 rows
    dim3 block(128);
    swt_inv_kernel<<<grid, block, 0, stream>>>(LL, LH, HL, HH, out);
}